// Round 9
// baseline (5917.470 us; speedup 1.0000x reference)
//
#include <hip/hip_runtime.h>

#define B_   128
#define T_   128
#define DIN  64
#define H_   1024
#define NBLK 256
#define NTHR 1024

typedef _Float16 f16;
typedef _Float16 half8 __attribute__((ext_vector_type(8)));
typedef float float4v __attribute__((ext_vector_type(4)));
typedef unsigned uint2v __attribute__((ext_vector_type(2)));
typedef unsigned uint4v __attribute__((ext_vector_type(4)));
typedef unsigned long long u64;

// R9: full-K geometry (R2-proven) + system-scope coherence (R6-proven, no
// invalidates) + TREE BARRIER v7 (zero serialized RMWs):
//   arrive: per-block own-line flag ARR[xcc][rank]  (parallel stores)
//   leader(rank 0): 32-thread gather of local arrives -> D[xcc]
//   root leader: 16-thread gather of D -> REL; leaders poll REL -> G[xcc]
//   blocks poll local G (v4 pattern). ~4 parallel fabric RTs, no RMW chains.
//
// h layout (block-major): h(m,col) at buf[(col>>2)*512 + m*4 + (col&3)];
// block bid writes region bid (contiguous 1KB), system-scope stores;
// consumers read via system-scope loads (always IF-coherent).
#define OFF_W2    34816
#define OFF_SG1A  100352
#define OFF_SG1B  109056
#define OFF_SG2A  117760
#define OFF_SG2B  126464
#define OFF_C1    135168
#define OFF_C2    137216
#define OFF_B1    139264
#define OFF_B2    139328
#define SMEM_BYTES 139392

// S layout (u32[32768], 128 KB):
//  ARR(x,r) = S[(x*32+r)*32]   x<16, r<32   arrive flags, one line each
//  D(x)     = S[16384 + x*32]               per-XCD done
//  REL      = S[17408]                      global release
//  G(x)     = S[18432 + x*32]               per-XCD go
//  CNT(x)   = S[20480 + x]                  block count / rank (preamble)

struct Params {
  const float *x, *Wih1, *Whh1, *bih1, *bhh1, *Wih2, *Whh2, *bih2, *bhh2,
              *Wlin, *blin, *Whio, *bhio;
  const int* fut;
  float* out;
  f16 *x16, *h1a, *h1b, *h2a, *h2b, *ob;
  unsigned *arrive, *rel;
  unsigned *S;
};

__device__ __forceinline__ float sigm(float v) { return 1.f / (1.f + __expf(-v)); }
__device__ __forceinline__ float tanh_(float v) { return 2.f / (1.f + __expf(-2.f * v)) - 1.f; }

__device__ __forceinline__ unsigned get_xcc() {
  unsigned x;
  asm volatile("s_getreg_b32 %0, hwreg(HW_REG_XCC_ID)" : "=s"(x));
  return x & 15u;
}

__device__ __forceinline__ u64 sysld(const void* p_) {
  return __hip_atomic_load((const u64*)p_, __ATOMIC_RELAXED, __HIP_MEMORY_SCOPE_SYSTEM);
}
__device__ __forceinline__ void sysst(void* p_, u64 v) {
  __hip_atomic_store((u64*)p_, v, __ATOMIC_RELAXED, __HIP_MEMORY_SCOPE_SYSTEM);
}

// ---- slow barrier (preamble only) -----------------------------------------
__device__ __forceinline__ void grid_sync(unsigned* arrive, unsigned* rel, unsigned ph) {
  __syncthreads();
  const int tid = threadIdx.x, bid = blockIdx.x;
  if (bid == 0) {
    if (tid > 0 && tid < NBLK) {
      while (__hip_atomic_load(&arrive[tid], __ATOMIC_RELAXED, __HIP_MEMORY_SCOPE_AGENT) != ph)
        __builtin_amdgcn_s_sleep(8);
    }
    __syncthreads();
    if (tid == 0)
      __hip_atomic_store(rel, ph, __ATOMIC_RELEASE, __HIP_MEMORY_SCOPE_AGENT);
  } else {
    if (tid == 0) {
      __hip_atomic_store(&arrive[bid], ph, __ATOMIC_RELEASE, __HIP_MEMORY_SCOPE_AGENT);
      while (__hip_atomic_load(rel, __ATOMIC_RELAXED, __HIP_MEMORY_SCOPE_AGENT) != ph)
        __builtin_amdgcn_s_sleep(8);
    }
  }
  __syncthreads();
  __builtin_amdgcn_fence(__ATOMIC_ACQUIRE, "agent");
}

__global__ void __launch_bounds__(NTHR, 4) lstm_k(Params p) {
  extern __shared__ char smem[];
  f16*   W1s  = (f16*)(smem);
  f16*   W2s  = (f16*)(smem + OFF_W2);
  float* Sg1A = (float*)(smem + OFF_SG1A);
  float* Sg1B = (float*)(smem + OFF_SG1B);
  float* Sg2A = (float*)(smem + OFF_SG2A);
  float* Sg2B = (float*)(smem + OFF_SG2B);
  float* c1   = (float*)(smem + OFF_C1);
  float* c2   = (float*)(smem + OFF_C2);
  float* bs1  = (float*)(smem + OFF_B1);
  float* bs2  = (float*)(smem + OFF_B2);
  __shared__ unsigned s_rank;

  const int tid = threadIdx.x, bid = blockIdx.x;
  const int hb  = bid * 4;
  const int fut = p.fut[0];
  const unsigned xcc = get_xcc();
  unsigned* S = p.S;

  if (bid == 0) {
    for (int i = tid; i < 32768; i += NTHR)
      __hip_atomic_store(&S[i], 0u, __ATOMIC_RELAXED, __HIP_MEMORY_SCOPE_AGENT);
  }

  // ---------------- preamble (R2-proven weight layout) -----------------------
  for (int idx = tid; idx < 34 * 512; idx += NTHR) {
    int c = idx >> 9, r = idx & 511;
    int q = r >> 7, colw = (r >> 3) & 15, j = r & 7;
    int k = c * 32 + q * 8 + j;
    int row = (colw >> 2) * H_ + hb + (colw & 3);
    float v = (k < H_) ? p.Whh1[row * H_ + k] : p.Wih1[row * DIN + (k - H_)];
    W1s[idx] = (f16)v;
  }
  for (int idx = tid; idx < 64 * 512; idx += NTHR) {
    int c = idx >> 9, r = idx & 511;
    int q = r >> 7, colw = (r >> 3) & 15, j = r & 7;
    int k = c * 32 + q * 8 + j;
    int row = (colw >> 2) * H_ + hb + (colw & 3);
    float v = (k < H_) ? p.Wih2[row * H_ + k] : p.Whh2[row * H_ + (k - H_)];
    W2s[idx] = (f16)v;
  }
  if (tid < 16) {
    int row = (tid >> 2) * H_ + hb + (tid & 3);
    bs1[tid] = p.bih1[row] + p.bhh1[row];
    bs2[tid] = p.bih2[row] + p.bhh2[row];
  }
  for (int i = tid; i < 512; i += NTHR) { c1[i] = 0.f; c2[i] = 0.f; }
  for (int i = bid * NTHR + tid; i < B_ * T_ * DIN; i += NBLK * NTHR)
    p.x16[i] = (f16)p.x[i];
  for (int i = bid * NTHR + tid; i < B_ * H_ / 4; i += NBLK * NTHR) {
    sysst((u64*)p.h1a + i, 0ull); sysst((u64*)p.h1b + i, 0ull);
    sysst((u64*)p.h2a + i, 0ull); sysst((u64*)p.h2b + i, 0ull);
  }

  unsigned gph = 1;
  grid_sync(p.arrive, p.rel, gph);
  if (tid == 0)
    s_rank = __hip_atomic_fetch_add(&S[20480 + xcc], 1u, __ATOMIC_RELAXED, __HIP_MEMORY_SCOPE_AGENT);
  ++gph;
  grid_sync(p.arrive, p.rel, gph);   // s_rank visible block-wide after this

  const unsigned rank = s_rank;
  const bool lead = (rank == 0);
  const unsigned xtotal = __hip_atomic_load(&S[20480 + xcc], __ATOMIC_RELAXED, __HIP_MEMORY_SCOPE_AGENT);
  unsigned occ = 0, rootx = 15;
  for (int i = 0; i < 16; ++i) {
    unsigned n = __hip_atomic_load(&S[20480 + i], __ATOMIC_RELAXED, __HIP_MEMORY_SCOPE_AGENT);
    if (n) { occ |= (1u << i); if ((unsigned)i < rootx) rootx = i; }
  }

  unsigned ph = 0;

  // ---- tree barrier v7: no serialized RMWs, ~4 parallel fabric RTs --------
  auto gsync = [&]() {
    ++ph;
    __syncthreads();
    if (tid == 0)
      __hip_atomic_store(&S[(xcc * 32 + rank) * 32], ph, __ATOMIC_RELEASE, __HIP_MEMORY_SCOPE_AGENT);
    if (lead) {
      if (tid < (int)xtotal) {
        while (__hip_atomic_load(&S[(xcc * 32 + tid) * 32], __ATOMIC_RELAXED, __HIP_MEMORY_SCOPE_AGENT) < ph)
          __builtin_amdgcn_s_sleep(1);
      }
      __syncthreads();
      if (tid == 0)
        __hip_atomic_store(&S[16384 + xcc * 32], ph, __ATOMIC_RELEASE, __HIP_MEMORY_SCOPE_AGENT);
      if (xcc == rootx) {
        if (tid < 16 && ((occ >> tid) & 1u)) {
          while (__hip_atomic_load(&S[16384 + tid * 32], __ATOMIC_RELAXED, __HIP_MEMORY_SCOPE_AGENT) < ph)
            __builtin_amdgcn_s_sleep(1);
        }
        __syncthreads();
        if (tid == 0)
          __hip_atomic_store(&S[17408], ph, __ATOMIC_RELEASE, __HIP_MEMORY_SCOPE_AGENT);
      } else {
        if (tid == 0) {
          while (__hip_atomic_load(&S[17408], __ATOMIC_RELAXED, __HIP_MEMORY_SCOPE_AGENT) < ph)
            __builtin_amdgcn_s_sleep(1);
        }
      }
      if (tid == 0)
        __hip_atomic_store(&S[18432 + xcc * 32], ph, __ATOMIC_RELEASE, __HIP_MEMORY_SCOPE_AGENT);
    } else {
      if (tid == 0) {
        while (__hip_atomic_load(&S[18432 + xcc * 32], __ATOMIC_ACQUIRE, __HIP_MEMORY_SCOPE_AGENT) < ph)
          __builtin_amdgcn_s_sleep(1);
      }
    }
    __syncthreads();
  };

  // ---------- wave geometry: 16 waves = 8 m-tiles x 2 K-halves -------------
  const int lane = tid & 63, wq = tid >> 6;
  const int g  = wq >> 3;        // K-half group (windows jb..jb+15)
  const int wv = wq & 7;
  const int col = lane & 15, quad = lane >> 4;
  const int m0 = wv * 16 + col;
  const int ko = quad * 8;
  const int jb = g * 16;
  const float b1v = g ? 0.f : bs1[col];   // bias only in K-half 0
  const float b2v = g ? 0.f : bs2[col];
  const f16* W1f = W1s + lane * 8;
  const f16* W2f = W2s + lane * 8;
  float* S1w = g ? Sg1B : Sg1A;
  float* S2w = g ? Sg2B : Sg2A;
  const int hoff = quad * 1024 + m0 * 4;

  f16 *h1c = p.h1a, *h1n = p.h1b, *h2c = p.h2a, *h2n = p.h2b;

  auto lstm_pw = [&](const float* SgA, const float* SgB, float* cst, f16* hn) {
    int idx = tid & 511;
    int mm = idx >> 2, cc = idx & 3;
    int i0 = mm * 17 + cc;
    float gi = SgA[i0]      + SgB[i0];
    float gf = SgA[i0 + 4]  + SgB[i0 + 4];
    float gg = SgA[i0 + 8]  + SgB[i0 + 8];
    float go = SgA[i0 + 12] + SgB[i0 + 12];
    float cn = sigm(gf) * cst[idx] + sigm(gi) * tanh_(gg);
    cst[idx] = cn;
    f16 hv = (f16)(sigm(go) * tanh_(cn));
    int v = (int)__builtin_bit_cast(unsigned short, hv);
    int base = lane & ~3;
    int v0 = __shfl(v, base, 64),     v1 = __shfl(v, base + 1, 64);
    int v2 = __shfl(v, base + 2, 64), v3 = __shfl(v, base + 3, 64);
    if (cc == 0) {
      u64 pk = (u64)(unsigned short)v0
        | ((u64)(unsigned short)v1 << 16)
        | ((u64)(unsigned short)v2 << 32)
        | ((u64)(unsigned short)v3 << 48);
      sysst(hn + bid * 512 + mm * 4, pk);
    }
  };

  auto ldwin = [&](const f16* hX, int j) -> half8 {
    u64 u0 = sysld(hX + j * 4096 + hoff);
    u64 u1 = sysld(hX + j * 4096 + hoff + 512);
    uint2v a0 = __builtin_bit_cast(uint2v, u0);
    uint2v a1 = __builtin_bit_cast(uint2v, u1);
    uint4v u = {a0[0], a0[1], a1[0], a1[1]};
    return __builtin_bit_cast(half8, u);
  };

  // fused phase: gates1(t+1) [l1] and gates2(t) [l2], both keyed on h1c.
  auto phase = [&](bool l1, bool l2, const f16* xp, int xstr, bool xb) {
    float4v a1 = {b1v, b1v, b1v, b1v};
    float4v a2 = {b2v, b2v, b2v, b2v};

    if (l1) {
      half8 ax;
      if (xb) {
        u64 u0 = sysld(xp + m0 * xstr + g * 32 + ko);
        u64 u1 = sysld(xp + m0 * xstr + g * 32 + ko + 4);
        uint2v a0 = __builtin_bit_cast(uint2v, u0);
        uint2v a1v = __builtin_bit_cast(uint2v, u1);
        uint4v u = {a0[0], a0[1], a1v[0], a1v[1]};
        ax = __builtin_bit_cast(half8, u);
      } else {
        ax = *(const half8*)(xp + m0 * xstr + g * 32 + ko);
      }
      a1 = __builtin_amdgcn_mfma_f32_16x16x32_f16(ax, *(const half8*)(W1f + (32 + g) * 512), a1, 0, 0, 0);
    }
    if (l1 && l2) {
      #pragma unroll
      for (int i = 0; i < 16; ++i) {
        int j = jb + i;
        half8 w1 = ldwin(h1c, j);
        half8 w2 = ldwin(h2c, j);
        a1 = __builtin_amdgcn_mfma_f32_16x16x32_f16(w1, *(const half8*)(W1f + j * 512), a1, 0, 0, 0);
        a2 = __builtin_amdgcn_mfma_f32_16x16x32_f16(w1, *(const half8*)(W2f + j * 512), a2, 0, 0, 0);
        a2 = __builtin_amdgcn_mfma_f32_16x16x32_f16(w2, *(const half8*)(W2f + (32 + j) * 512), a2, 0, 0, 0);
      }
    } else if (l1) {
      #pragma unroll
      for (int i = 0; i < 16; ++i) {
        int j = jb + i;
        half8 w1 = ldwin(h1c, j);
        a1 = __builtin_amdgcn_mfma_f32_16x16x32_f16(w1, *(const half8*)(W1f + j * 512), a1, 0, 0, 0);
      }
    } else if (l2) {
      #pragma unroll
      for (int i = 0; i < 16; ++i) {
        int j = jb + i;
        half8 w1 = ldwin(h1c, j);
        half8 w2 = ldwin(h2c, j);
        a2 = __builtin_amdgcn_mfma_f32_16x16x32_f16(w1, *(const half8*)(W2f + j * 512), a2, 0, 0, 0);
        a2 = __builtin_amdgcn_mfma_f32_16x16x32_f16(w2, *(const half8*)(W2f + (32 + j) * 512), a2, 0, 0, 0);
      }
    }

    // ---- merged epilogue: partial-gate staging + parallel pointwise ----
    __syncthreads();
    if (l1) {
      #pragma unroll
      for (int r = 0; r < 4; ++r)
        S1w[(wv * 16 + quad * 4 + r) * 17 + col] = a1[r];
    }
    if (l2) {
      #pragma unroll
      for (int r = 0; r < 4; ++r)
        S2w[(wv * 16 + quad * 4 + r) * 17 + col] = a2[r];
    }
    __syncthreads();
    if (tid < 512) {
      if (l1) lstm_pw(Sg1A, Sg1B, c1, h1n);
    } else {
      if (l2) lstm_pw(Sg2A, Sg2B, c2, h2n);
    }
  };

  // small projection: out[m][j] = h2 . W[j] + b[j]  (system h2 reads)
  auto out_phase = [&](const float* W, const float* bv, bool wout) {
    if (tid >= 512) return;
    int j = bid & 63, mgp = bid >> 6;
    int rid = tid >> 4, ks = tid & 15;
    int mrow = mgp * 32 + rid;
    const float* wr = W + j * H_ + ks * 64;
    float sacc = 0.f;
    #pragma unroll
    for (int q = 0; q < 16; ++q) {
      u64 uv = sysld(h2c + (ks * 16 + q) * 512 + mrow * 4);
      uint2v uu = __builtin_bit_cast(uint2v, uv);
      half8 hv4;
      { uint4v t = {uu[0], uu[1], 0u, 0u}; hv4 = __builtin_bit_cast(half8, t); }
      sacc += (float)hv4[0] * wr[q * 4 + 0] + (float)hv4[1] * wr[q * 4 + 1]
            + (float)hv4[2] * wr[q * 4 + 2] + (float)hv4[3] * wr[q * 4 + 3];
    }
    sacc += __shfl_down(sacc, 8, 16);
    sacc += __shfl_down(sacc, 4, 16);
    sacc += __shfl_down(sacc, 2, 16);
    sacc += __shfl_down(sacc, 1, 16);
    if (ks == 0) {
      float v = sacc + bv[j];
      f16 hv = (f16)v;
      unsigned short hb16 = __builtin_bit_cast(unsigned short, hv);
      __hip_atomic_store((unsigned short*)&p.ob[mrow * 64 + j], hb16,
                         __ATOMIC_RELAXED, __HIP_MEMORY_SCOPE_SYSTEM);
      if (wout) p.out[mrow * 64 + j] = v;
    }
  };

  // ---------------- time loop: 129 fused phases ----------------------------
  for (int t = -1; t < T_; ++t) {
    bool l1 = (t + 1 < T_), l2 = (t >= 0);
    phase(l1, l2, p.x16 + (t + 1) * DIN, T_ * DIN, false);
    gsync();
    if (l1) { f16* tm = h1c; h1c = h1n; h1n = tm; }
    if (l2) { f16* tm = h2c; h2c = h2n; h2n = tm; }
  }
  out_phase(p.Wlin, p.blin, fut == 0);
  gsync();
  for (int f = 0; f < fut; ++f) {
    phase(true, false, p.ob, 64, true);
    gsync();
    { f16* tm = h1c; h1c = h1n; h1n = tm; }
    phase(false, true, p.ob, 64, true);
    gsync();
    { f16* tm = h2c; h2c = h2n; h2n = tm; }
    out_phase(p.Whio, p.bhio, f == fut - 1);
    gsync();
  }
}

extern "C" void kernel_launch(void* const* d_in, const int* in_sizes, int n_in,
                              void* d_out, int out_size, void* d_ws, size_t ws_size,
                              hipStream_t stream) {
  char* w = (char*)d_ws;
  auto carve = [&](size_t n) { char* r = w; w += (n + 255) & ~(size_t)255; return r; };

  Params p;
  p.x    = (const float*)d_in[0];
  p.Wih1 = (const float*)d_in[1];
  p.Whh1 = (const float*)d_in[2];
  p.bih1 = (const float*)d_in[3];
  p.bhh1 = (const float*)d_in[4];
  p.Wih2 = (const float*)d_in[5];
  p.Whh2 = (const float*)d_in[6];
  p.bih2 = (const float*)d_in[7];
  p.bhh2 = (const float*)d_in[8];
  p.Wlin = (const float*)d_in[9];
  p.blin = (const float*)d_in[10];
  p.Whio = (const float*)d_in[11];
  p.bhio = (const float*)d_in[12];
  p.fut  = (const int*)d_in[13];
  p.out  = (float*)d_out;

  p.x16 = (f16*)carve((size_t)B_ * T_ * DIN * 2);
  p.h1a = (f16*)carve((size_t)B_ * H_ * 2);
  p.h1b = (f16*)carve((size_t)B_ * H_ * 2);
  p.h2a = (f16*)carve((size_t)B_ * H_ * 2);
  p.h2b = (f16*)carve((size_t)B_ * H_ * 2);
  p.ob  = (f16*)carve((size_t)B_ * 64 * 2);
  p.arrive = (unsigned*)carve(NBLK * sizeof(unsigned));
  p.rel    = (unsigned*)carve(256);
  p.S      = (unsigned*)carve(32768 * sizeof(unsigned));

  (void)hipFuncSetAttribute((const void*)lstm_k,
                            hipFuncAttributeMaxDynamicSharedMemorySize, SMEM_BYTES);
  void* args[] = { &p };
  (void)hipLaunchCooperativeKernel((void*)lstm_k, dim3(NBLK), dim3(NTHR),
                                   args, SMEM_BYTES, stream);
}

// Round 10
// 1861.284 us; speedup vs baseline: 3.1792x; 3.1792x over previous
//
#include <hip/hip_runtime.h>

#define B_   128
#define T_   128
#define DIN  64
#define H_   1024
#define NBLK 256
#define NTHR 1024

typedef _Float16 f16;
typedef _Float16 half8 __attribute__((ext_vector_type(8)));
typedef float float4v __attribute__((ext_vector_type(4)));
typedef unsigned uint2v __attribute__((ext_vector_type(2)));
typedef unsigned uint4v __attribute__((ext_vector_type(4)));
typedef unsigned long long u64;

// FINAL (R10 = R6 verbatim, session best 1856.8 µs):
// Pair K-split decomposition (R5):
//   c = bid & 127 : column group; g = bid >> 7 : K-half; partner = bid^128.
//   block owns h write region cb = c*2+g (4 cols, contiguous 1KB).
// NO cache invalidates. All cross-phase-mutable data (h buffers, PB partials,
// FL flags, ob) accessed with SYSTEM-scope (cache-bypassing) atomics ->
// always coherent at the IF point. Barrier = v4 ticket structure minus invs
// (empirically the fastest of 5 sync designs tested; tree/flag-array/dataflow
// alternatives all regressed 2-9x).
#define OFF_W2    34816
#define OFF_SG1A  100352
#define OFF_SG1B  109056
#define OFF_SG2A  117760
#define OFF_SG2B  126464
#define OFF_C1    135168
#define OFF_C2    137216
#define OFF_B1    139264
#define OFF_B2    139328
#define SMEM_BYTES 139392

struct Params {
  const float *x, *Wih1, *Whh1, *bih1, *bhh1, *Wih2, *Whh2, *bih2, *bhh2,
              *Wlin, *blin, *Whio, *bhio;
  const int* fut;
  float* out;
  f16 *x16, *h1a, *h1b, *h2a, *h2b, *ob;
  unsigned *arrive, *rel;
  unsigned *S;
  float* PB;      // partner partials: [c][dg][s][layer][128][16] f32, 8 MB
  unsigned* FL;   // per-block phase flag, one 128B line each: FL[bid*32]
};

__device__ __forceinline__ float sigm(float v) { return 1.f / (1.f + __expf(-v)); }
__device__ __forceinline__ float tanh_(float v) { return 2.f / (1.f + __expf(-2.f * v)) - 1.f; }

__device__ __forceinline__ unsigned get_xcc() {
  unsigned x;
  asm volatile("s_getreg_b32 %0, hwreg(HW_REG_XCC_ID)" : "=s"(x));
  return x & 15u;
}

__device__ __forceinline__ u64 sysld(const void* p_) {
  return __hip_atomic_load((const u64*)p_, __ATOMIC_RELAXED, __HIP_MEMORY_SCOPE_SYSTEM);
}
__device__ __forceinline__ void sysst(void* p_, u64 v) {
  __hip_atomic_store((u64*)p_, v, __ATOMIC_RELAXED, __HIP_MEMORY_SCOPE_SYSTEM);
}

// ---- slow barrier (preamble only) -----------------------------------------
__device__ __forceinline__ void grid_sync(unsigned* arrive, unsigned* rel, unsigned ph) {
  __syncthreads();
  const int tid = threadIdx.x, bid = blockIdx.x;
  if (bid == 0) {
    if (tid > 0 && tid < NBLK) {
      while (__hip_atomic_load(&arrive[tid], __ATOMIC_RELAXED, __HIP_MEMORY_SCOPE_AGENT) != ph)
        __builtin_amdgcn_s_sleep(8);
    }
    __syncthreads();
    if (tid == 0)
      __hip_atomic_store(rel, ph, __ATOMIC_RELEASE, __HIP_MEMORY_SCOPE_AGENT);
  } else {
    if (tid == 0) {
      __hip_atomic_store(&arrive[bid], ph, __ATOMIC_RELEASE, __HIP_MEMORY_SCOPE_AGENT);
      while (__hip_atomic_load(rel, __ATOMIC_RELAXED, __HIP_MEMORY_SCOPE_AGENT) != ph)
        __builtin_amdgcn_s_sleep(8);
    }
  }
  __syncthreads();
  __builtin_amdgcn_fence(__ATOMIC_ACQUIRE, "agent");
}

// ---- fast barrier v6: v4 ticket structure, NO invalidates -----------------
__device__ __forceinline__ void fast_sync(unsigned* S, unsigned x, unsigned xtotal,
                                          unsigned nxcd, unsigned ph) {
  __syncthreads();
  if (threadIdx.x == 0) {
    unsigned t = __hip_atomic_fetch_add(&S[x * 32], 1u, __ATOMIC_RELAXED, __HIP_MEMORY_SCOPE_AGENT);
    bool leader = (t % xtotal == 0u);
    if ((t + 1u) % xtotal == 0u) {
      unsigned c = __hip_atomic_fetch_add(&S[512], 1u, __ATOMIC_RELAXED, __HIP_MEMORY_SCOPE_AGENT);
      if ((c + 1u) % nxcd == 0u)
        __hip_atomic_store(&S[544], ph, __ATOMIC_RELAXED, __HIP_MEMORY_SCOPE_AGENT);
      __hip_atomic_store(&S[1088 + x * 32], ph, __ATOMIC_RELAXED, __HIP_MEMORY_SCOPE_AGENT);
    }
    if (leader) {
      while (__hip_atomic_load(&S[544], __ATOMIC_RELAXED, __HIP_MEMORY_SCOPE_AGENT) != ph)
        __builtin_amdgcn_s_sleep(1);
      while (__hip_atomic_load(&S[1088 + x * 32], __ATOMIC_RELAXED, __HIP_MEMORY_SCOPE_AGENT) != ph)
        __builtin_amdgcn_s_sleep(1);
      __hip_atomic_store(&S[576 + x * 32], ph, __ATOMIC_RELAXED, __HIP_MEMORY_SCOPE_AGENT);
    } else {
      while (__hip_atomic_load(&S[576 + x * 32], __ATOMIC_RELAXED, __HIP_MEMORY_SCOPE_AGENT) != ph)
        __builtin_amdgcn_s_sleep(2);
    }
  }
  __syncthreads();
}

__global__ void __launch_bounds__(NTHR, 4) lstm_k(Params p) {
  extern __shared__ char smem[];
  f16*   W1s  = (f16*)(smem);
  f16*   W2s  = (f16*)(smem + OFF_W2);
  float* Sg1A = (float*)(smem + OFF_SG1A);
  float* Sg1B = (float*)(smem + OFF_SG1B);
  float* Sg2A = (float*)(smem + OFF_SG2A);
  float* Sg2B = (float*)(smem + OFF_SG2B);
  float* c1   = (float*)(smem + OFF_C1);
  float* c2   = (float*)(smem + OFF_C2);
  float* bs1  = (float*)(smem + OFF_B1);
  float* bs2  = (float*)(smem + OFF_B2);

  const int tid = threadIdx.x, bid = blockIdx.x;
  const int c   = bid & 127;          // column group (8 cols)
  const int g   = bid >> 7;           // K-half
  const int bidp = bid ^ 128;         // pair partner
  const int cb  = c * 2 + g;          // owned h write region (4 cols)
  const int fut = p.fut[0];
  const unsigned xcc = get_xcc();
  unsigned* S = p.S;

  if (bid == 0) {
    for (int i = tid; i < 2048; i += NTHR)
      __hip_atomic_store(&S[i], 0u, __ATOMIC_RELAXED, __HIP_MEMORY_SCOPE_AGENT);
  }
  // zero pair flags (system scope -> visible to bypass polls)
  for (int i = bid * NTHR + tid; i < 256 * 32 / 2; i += NBLK * NTHR)
    sysst(&p.FL[i * 2], 0ull);

  // ---------------- preamble: weights ---------------------------------------
  for (int idx = tid; idx < 17 * 2 * 512; idx += NTHR) {
    int j2 = idx >> 9, r = idx & 511;
    int j = j2 >> 1, nt = j2 & 1;
    int lane_ = r >> 3, jj = r & 7;
    int q = lane_ >> 4, colw = lane_ & 15;
    int row = (colw >> 2) * H_ + c * 8 + nt * 4 + (colw & 3);
    float v = (j < 16) ? p.Whh1[row * H_ + g * 512 + j * 32 + q * 8 + jj]
                       : p.Wih1[row * DIN + g * 32 + q * 8 + jj];
    W1s[idx] = (f16)v;
  }
  for (int idx = tid; idx < 32 * 2 * 512; idx += NTHR) {
    int j2 = idx >> 9, r = idx & 511;
    int j = j2 >> 1, nt = j2 & 1;
    int lane_ = r >> 3, jj = r & 7;
    int q = lane_ >> 4, colw = lane_ & 15;
    int row = (colw >> 2) * H_ + c * 8 + nt * 4 + (colw & 3);
    float v = (j < 16) ? p.Wih2[row * H_ + g * 512 + j * 32 + q * 8 + jj]
                       : p.Whh2[row * H_ + g * 512 + (j - 16) * 32 + q * 8 + jj];
    W2s[idx] = (f16)v;
  }
  if (tid < 16) {
    int row = (tid >> 2) * H_ + c * 8 + g * 4 + (tid & 3);
    bs1[tid] = p.bih1[row] + p.bhh1[row];
    bs2[tid] = p.bih2[row] + p.bhh2[row];
  }
  for (int i = tid; i < 512; i += NTHR) { c1[i] = 0.f; c2[i] = 0.f; }
  for (int i = bid * NTHR + tid; i < B_ * T_ * DIN; i += NBLK * NTHR)
    p.x16[i] = (f16)p.x[i];
  // h zero-init via system stores (visible to bypass reads)
  for (int i = bid * NTHR + tid; i < B_ * H_ / 4; i += NBLK * NTHR) {
    sysst((u64*)p.h1a + i, 0ull); sysst((u64*)p.h1b + i, 0ull);
    sysst((u64*)p.h2a + i, 0ull); sysst((u64*)p.h2b + i, 0ull);
  }

  unsigned ph = 1;
  grid_sync(p.arrive, p.rel, ph);
  if (tid == 0)
    __hip_atomic_fetch_add(&S[1600 + xcc], 1u, __ATOMIC_RELAXED, __HIP_MEMORY_SCOPE_AGENT);
  ++ph;
  grid_sync(p.arrive, p.rel, ph);

  unsigned xtotal = __hip_atomic_load(&S[1600 + xcc], __ATOMIC_RELAXED, __HIP_MEMORY_SCOPE_AGENT);
  unsigned nxcd = 0;
  for (int i = 0; i < 16; ++i)
    nxcd += (__hip_atomic_load(&S[1600 + i], __ATOMIC_RELAXED, __HIP_MEMORY_SCOPE_AGENT) != 0u);

  auto gsync = [&]() { ++ph; fast_sync(S, xcc, xtotal, nxcd, ph); };

  // ---------- wave geometry: 16 waves = 8 m-tiles x 2 sub-halves -----------
  const int lane = tid & 63, wq = tid >> 6;
  const int s  = wq >> 3;
  const int wv = wq & 7;
  const int col = lane & 15, quad = lane >> 4;
  const int m0 = wv * 16 + col;
  const int ko = quad * 8;
  const f16* W1f = W1s + lane * 8;
  const f16* W2f = W2s + lane * 8;
  float* S1w = s ? Sg1B : Sg1A;
  float* S2w = s ? Sg2B : Sg2A;
  const int hoff = quad * 1024 + m0 * 4;

  auto PBidx = [](int cg, int dg, int ss, int ll) {
    return ((((cg * 2 + dg) * 2 + ss) * 2 + ll) * 2048);
  };

  f16 *h1c = p.h1a, *h1n = p.h1b, *h2c = p.h2a, *h2n = p.h2b;
  unsigned pcnt = 0;

  // pointwise: own LDS partials (both subs) + partner global (bypass reads)
  auto lstm_pw = [&](const float* SgA, const float* SgB, float* Pb0, float* Pb1,
                     const float* bsX, float* cst, f16* hn) {
    int idx = tid & 511;
    int mm = idx >> 2, cc = idx & 3;
    int i0 = mm * 17 + cc;
    int pb = mm * 16 + cc;
    float gq[4];
    #pragma unroll
    for (int q = 0; q < 4; ++q) {
      float pv0 = __hip_atomic_load(Pb0 + pb + q * 4, __ATOMIC_RELAXED, __HIP_MEMORY_SCOPE_SYSTEM);
      float pv1 = __hip_atomic_load(Pb1 + pb + q * 4, __ATOMIC_RELAXED, __HIP_MEMORY_SCOPE_SYSTEM);
      gq[q] = SgA[i0 + q * 4] + SgB[i0 + q * 4] + pv0 + pv1 + bsX[q * 4 + cc];
    }
    float cn = sigm(gq[1]) * cst[idx] + sigm(gq[0]) * tanh_(gq[2]);
    cst[idx] = cn;
    f16 hv = (f16)(sigm(gq[3]) * tanh_(cn));
    int v = (int)__builtin_bit_cast(unsigned short, hv);
    int base = lane & ~3;
    int v0 = __shfl(v, base, 64),     v1 = __shfl(v, base + 1, 64);
    int v2 = __shfl(v, base + 2, 64), v3 = __shfl(v, base + 3, 64);
    if (cc == 0) {
      u64 pk = (u64)(unsigned short)v0
        | ((u64)(unsigned short)v1 << 16)
        | ((u64)(unsigned short)v2 << 32)
        | ((u64)(unsigned short)v3 << 48);
      sysst(hn + cb * 512 + mm * 4, pk);
    }
  };

  // bypass (system-scope) 16B h window read
  auto ldwin = [&](const f16* hX, int j) -> half8 {
    u64 u0 = sysld(hX + j * 4096 + hoff);
    u64 u1 = sysld(hX + j * 4096 + hoff + 512);
    uint2v a0 = __builtin_bit_cast(uint2v, u0);
    uint2v a1 = __builtin_bit_cast(uint2v, u1);
    uint4v u = {a0[0], a0[1], a1[0], a1[1]};
    return __builtin_bit_cast(half8, u);
  };

  // fused phase; xb=true -> x input is ob (mutable, needs bypass reads)
  auto phase = [&](bool l1, bool l2, const f16* xp, int xstr, bool xb) {
    ++pcnt;
    float4v a1A = {0,0,0,0}, a1B = {0,0,0,0};
    float4v a2A = {0,0,0,0}, a2B = {0,0,0,0};

    if (l1 && s == 0) {
      half8 ax;
      if (xb) {
        u64 u0 = sysld(xp + m0 * xstr + g * 32 + ko);
        u64 u1 = sysld(xp + m0 * xstr + g * 32 + ko + 4);
        uint2v a0 = __builtin_bit_cast(uint2v, u0);
        uint2v a1v = __builtin_bit_cast(uint2v, u1);
        uint4v u = {a0[0], a0[1], a1v[0], a1v[1]};
        ax = __builtin_bit_cast(half8, u);
      } else {
        ax = *(const half8*)(xp + m0 * xstr + g * 32 + ko);
      }
      a1A = __builtin_amdgcn_mfma_f32_16x16x32_f16(ax, *(const half8*)(W1f + 32 * 512), a1A, 0, 0, 0);
      a1B = __builtin_amdgcn_mfma_f32_16x16x32_f16(ax, *(const half8*)(W1f + 33 * 512), a1B, 0, 0, 0);
    }
    #pragma unroll
    for (int i = 0; i < 8; ++i) {
      int j = s * 8 + i;
      int gw = g * 16 + j;
      half8 w1 = ldwin(h1c, gw);
      if (l1) {
        a1A = __builtin_amdgcn_mfma_f32_16x16x32_f16(w1, *(const half8*)(W1f + (j * 2) * 512), a1A, 0, 0, 0);
        a1B = __builtin_amdgcn_mfma_f32_16x16x32_f16(w1, *(const half8*)(W1f + (j * 2 + 1) * 512), a1B, 0, 0, 0);
      }
      if (l2) {
        half8 w2 = ldwin(h2c, gw);
        a2A = __builtin_amdgcn_mfma_f32_16x16x32_f16(w1, *(const half8*)(W2f + (j * 2) * 512), a2A, 0, 0, 0);
        a2B = __builtin_amdgcn_mfma_f32_16x16x32_f16(w1, *(const half8*)(W2f + (j * 2 + 1) * 512), a2B, 0, 0, 0);
        a2A = __builtin_amdgcn_mfma_f32_16x16x32_f16(w2, *(const half8*)(W2f + ((16 + j) * 2) * 512), a2A, 0, 0, 0);
        a2B = __builtin_amdgcn_mfma_f32_16x16x32_f16(w2, *(const half8*)(W2f + ((16 + j) * 2 + 1) * 512), a2B, 0, 0, 0);
      }
    }

    // ---- partner partials -> global (system write-through) ----
    {
      int mb = (wv * 16 + quad * 4) * 16 + col;
      if (l1) {
        float4v pa = g ? a1A : a1B;
        float* dst = p.PB + PBidx(c, 1 - g, s, 0) + mb;
        #pragma unroll
        for (int r = 0; r < 4; ++r)
          __hip_atomic_store(dst + r * 16, pa[r], __ATOMIC_RELAXED, __HIP_MEMORY_SCOPE_SYSTEM);
      }
      if (l2) {
        float4v pa = g ? a2A : a2B;
        float* dst = p.PB + PBidx(c, 1 - g, s, 1) + mb;
        #pragma unroll
        for (int r = 0; r < 4; ++r)
          __hip_atomic_store(dst + r * 16, pa[r], __ATOMIC_RELAXED, __HIP_MEMORY_SCOPE_SYSTEM);
      }
    }
    __syncthreads();   // drains vmcnt -> all partial stores visible
    if (tid == 0)
      __hip_atomic_store(&p.FL[bid * 32], pcnt, __ATOMIC_RELEASE, __HIP_MEMORY_SCOPE_SYSTEM);

    // ---- own-nt partials -> LDS staging ----
    if (l1) {
      float4v oa = g ? a1B : a1A;
      #pragma unroll
      for (int r = 0; r < 4; ++r)
        S1w[(wv * 16 + quad * 4 + r) * 17 + col] = oa[r];
    }
    if (l2) {
      float4v oa = g ? a2B : a2A;
      #pragma unroll
      for (int r = 0; r < 4; ++r)
        S2w[(wv * 16 + quad * 4 + r) * 17 + col] = oa[r];
    }
    __syncthreads();

    // ---- wait for partner's partials (bypass poll), then pointwise ----
    while (__hip_atomic_load(&p.FL[bidp * 32], __ATOMIC_RELAXED, __HIP_MEMORY_SCOPE_SYSTEM) < pcnt)
      __builtin_amdgcn_s_sleep(1);

    if (tid < 512) {
      if (l1) lstm_pw(Sg1A, Sg1B,
                      p.PB + PBidx(c, g, 0, 0), p.PB + PBidx(c, g, 1, 0),
                      bs1, c1, h1n);
    } else {
      if (l2) lstm_pw(Sg2A, Sg2B,
                      p.PB + PBidx(c, g, 0, 1), p.PB + PBidx(c, g, 1, 1),
                      bs2, c2, h2n);
    }
  };

  // small projection: out[m][j] = h2 . W[j] + b[j]  (bypass h2 reads)
  auto out_phase = [&](const float* W, const float* bv, bool wout) {
    if (tid >= 512) return;
    int j = bid & 63, mgp = bid >> 6;
    int rid = tid >> 4, ks = tid & 15;
    int mrow = mgp * 32 + rid;
    const float* wr = W + j * H_ + ks * 64;
    float sacc = 0.f;
    #pragma unroll
    for (int q = 0; q < 16; ++q) {
      u64 uv = sysld(h2c + (ks * 16 + q) * 512 + mrow * 4);
      uint2v uu = __builtin_bit_cast(uint2v, uv);
      half8 hv4;
      { uint4v t = {uu[0], uu[1], 0u, 0u}; hv4 = __builtin_bit_cast(half8, t); }
      sacc += (float)hv4[0] * wr[q * 4 + 0] + (float)hv4[1] * wr[q * 4 + 1]
            + (float)hv4[2] * wr[q * 4 + 2] + (float)hv4[3] * wr[q * 4 + 3];
    }
    sacc += __shfl_down(sacc, 8, 16);
    sacc += __shfl_down(sacc, 4, 16);
    sacc += __shfl_down(sacc, 2, 16);
    sacc += __shfl_down(sacc, 1, 16);
    if (ks == 0) {
      float v = sacc + bv[j];
      f16 hv = (f16)v;
      unsigned short hb16 = __builtin_bit_cast(unsigned short, hv);
      __hip_atomic_store((unsigned short*)&p.ob[mrow * 64 + j], hb16,
                         __ATOMIC_RELAXED, __HIP_MEMORY_SCOPE_SYSTEM);
      if (wout) p.out[mrow * 64 + j] = v;
    }
  };

  // ---------------- time loop: 129 fused phases ----------------------------
  for (int t = -1; t < T_; ++t) {
    bool l1 = (t + 1 < T_), l2 = (t >= 0);
    phase(l1, l2, p.x16 + (t + 1) * DIN, T_ * DIN, false);
    gsync();
    if (l1) { f16* tm = h1c; h1c = h1n; h1n = tm; }
    if (l2) { f16* tm = h2c; h2c = h2n; h2n = tm; }
  }
  out_phase(p.Wlin, p.blin, fut == 0);
  gsync();
  for (int f = 0; f < fut; ++f) {
    phase(true, false, p.ob, 64, true);
    gsync();
    { f16* tm = h1c; h1c = h1n; h1n = tm; }
    phase(false, true, p.ob, 64, true);
    gsync();
    { f16* tm = h2c; h2c = h2n; h2n = tm; }
    out_phase(p.Whio, p.bhio, f == fut - 1);
    gsync();
  }
}

extern "C" void kernel_launch(void* const* d_in, const int* in_sizes, int n_in,
                              void* d_out, int out_size, void* d_ws, size_t ws_size,
                              hipStream_t stream) {
  char* w = (char*)d_ws;
  auto carve = [&](size_t n) { char* r = w; w += (n + 255) & ~(size_t)255; return r; };

  Params p;
  p.x    = (const float*)d_in[0];
  p.Wih1 = (const float*)d_in[1];
  p.Whh1 = (const float*)d_in[2];
  p.bih1 = (const float*)d_in[3];
  p.bhh1 = (const float*)d_in[4];
  p.Wih2 = (const float*)d_in[5];
  p.Whh2 = (const float*)d_in[6];
  p.bih2 = (const float*)d_in[7];
  p.bhh2 = (const float*)d_in[8];
  p.Wlin = (const float*)d_in[9];
  p.blin = (const float*)d_in[10];
  p.Whio = (const float*)d_in[11];
  p.bhio = (const float*)d_in[12];
  p.fut  = (const int*)d_in[13];
  p.out  = (float*)d_out;

  p.x16 = (f16*)carve((size_t)B_ * T_ * DIN * 2);
  p.h1a = (f16*)carve((size_t)B_ * H_ * 2);
  p.h1b = (f16*)carve((size_t)B_ * H_ * 2);
  p.h2a = (f16*)carve((size_t)B_ * H_ * 2);
  p.h2b = (f16*)carve((size_t)B_ * H_ * 2);
  p.ob  = (f16*)carve((size_t)B_ * 64 * 2);
  p.arrive = (unsigned*)carve(NBLK * sizeof(unsigned));
  p.rel    = (unsigned*)carve(256);
  p.S      = (unsigned*)carve(2048 * sizeof(unsigned));
  p.PB     = (float*)carve((size_t)128 * 2 * 2 * 2 * 2048 * sizeof(float));  // 8 MB
  p.FL     = (unsigned*)carve((size_t)256 * 32 * sizeof(unsigned));          // 32 KB

  (void)hipFuncSetAttribute((const void*)lstm_k,
                            hipFuncAttributeMaxDynamicSharedMemorySize, SMEM_BYTES);
  void* args[] = { &p };
  (void)hipLaunchCooperativeKernel((void*)lstm_k, dim3(NBLK), dim3(NTHR),
                                   args, SMEM_BYTES, stream);
}